// Round 1
// baseline (104.135 us; speedup 1.0000x reference)
//
#include <hip/hip_runtime.h>

#define TT 1024
#define BB 8
#define II 1023
// output offsets (floats)
#define OFF_INTENS 0
#define OFF_MU     32736          // 8*1023*4
#define OFF_ALPHA  65504          // + 8*1024*4
#define OFF_DELTA  98240          // + 8*1023*4

__device__ __forceinline__ float softplus_f(float x) {
    return fmaxf(x, 0.f) + log1pf(expf(-fabsf(x)));
}

// One block. Waves: lane 0-7 -> sequential cumsum per batch (matches np.cumsum
// rounding exactly); tid 64..159 -> 96 alpha/delta table MLPs; 160..163 -> mu.
__global__ __launch_bounds__(256) void k_prep(
    const float* __restrict__ time_step,
    const float* __restrict__ mw1, const float* __restrict__ mb1,
    const float* __restrict__ mw2, const float* __restrict__ mb2,
    const float* __restrict__ aw1, const float* __restrict__ ab1,
    const float* __restrict__ aw2, const float* __restrict__ ab2,
    const float* __restrict__ dw1, const float* __restrict__ db1,
    const float* __restrict__ dw2, const float* __restrict__ db2,
    float* __restrict__ ws)
{
    __shared__ float lds[BB * TT];
    const int tid = threadIdx.x;
    for (int idx = tid; idx < BB * TT; idx += 256) lds[idx] = time_step[idx];
    __syncthreads();

    if (tid < 8) {
        // ws[0 .. 8191]: timestep (prefix sums), sequential fp32 per batch
        const int b = tid;
        float run = 0.f;
        ws[b * TT] = 0.f;
        for (int t = 1; t < TT; ++t) {
            run += lds[b * TT + t];
            ws[b * TT + t] = run;
        }
    } else if (tid >= 64 && tid < 160) {
        // 48 distinct (e,s,k) inputs for alpha (idx<48) and delta (idx>=48)
        const int idx = tid - 64;
        const int c   = (idx < 48) ? idx : idx - 48;   // (e*3+s)*4+k
        const bool isA = idx < 48;
        const float* w1 = isA ? aw1 : dw1;
        const float* b1 = isA ? ab1 : db1;
        const float* w2 = isA ? aw2 : dw2;
        const float* b2 = isA ? ab2 : db2;
        const int e = c / 12, s = (c % 12) >> 2, k = c & 3;
        float acc = 0.f;
        #pragma unroll
        for (int n = 0; n < 16; ++n) {
            // reference order: (((ev)+st)+eye)+b1
            float h = w1[e * 16 + n] + w1[(4 + s) * 16 + n] + w1[(7 + k) * 16 + n] + b1[n];
            acc += fmaxf(h, 0.f) * w2[n];
        }
        // ws[8192 + 2*c + {0:alpha,1:delta}] (float2-interleaved table)
        ws[BB * TT + 2 * c + (isA ? 0 : 1)] = softplus_f(acc + b2[0]);
    } else if (tid >= 160 && tid < 164) {
        const int k = tid - 160;
        float acc = 0.f;
        #pragma unroll
        for (int n = 0; n < 16; ++n)
            acc += fmaxf(mw1[k * 16 + n] + mb1[n], 0.f) * mw2[n];
        ws[BB * TT + 96 + k] = softplus_f(acc + mb2[0]);  // ws[8288+k]: mu_base
    }
}

// Grid (64 jt, 8 b), 256 threads. Thread map: bits[1:0]=s (i-split, i≡s mod 4),
// bits[3:2]=k, bits[7:4]=jj (j = 16*jt+jj). ad_l[i][k] float2 layout gives
// conflict-free ds_read_b64 (banks = (8s+2k)%32, all 16 (s,k) pairs distinct).
__global__ __launch_bounds__(256) void k_main(
    const int* __restrict__ event, const int* __restrict__ mkt,
    const float* __restrict__ ws, float* __restrict__ out)
{
    __shared__ float  ts_l[TT];
    __shared__ float2 ad_l[TT * 4];
    const int tid = threadIdx.x;
    const int b   = blockIdx.y;
    const int jt  = blockIdx.x;
    const float2* adtab = (const float2*)(ws + BB * TT);
    const float*  mu_g  = ws + BB * TT + 96;

    for (int t = tid; t < TT; t += 256) ts_l[t] = ws[b * TT + t];
    for (int idx = tid; idx < TT * 4; idx += 256) {
        const int i = idx >> 2, k = idx & 3;
        const int e = event[b * TT + i];
        const int s = mkt[b * TT + i];
        ad_l[idx] = adtab[(e * 3 + s) * 4 + k];
    }
    __syncthreads();

    const int s  = tid & 3;
    const int k  = (tid >> 2) & 3;
    const int jj = tid >> 4;
    const int j  = jt * 16 + jj;

    float acc = 0.f;
    if (j < II) {
        const float tsj1 = ts_l[j + 1];
        #pragma unroll 4
        for (int i = s; i <= j; i += 4) {
            const float2 ad = ad_l[(i << 2) | k];
            float dt = tsj1 - ts_l[i];
            dt = (dt > 0.f) ? dt : 1e9f;
            acc += ad.x * __expf(-ad.y * dt);
        }
    }
    acc += __shfl_xor(acc, 1, 64);
    acc += __shfl_xor(acc, 2, 64);

    const float muk = mu_g[k];
    if (j < II) {
        const int base = (b * II + j) * 4 + k;
        if (s == 0)      out[OFF_INTENS + base] = muk + acc;
        else if (s == 1) out[OFF_ALPHA  + base] = ad_l[(j << 2) | k].x;
        else if (s == 2) out[OFF_DELTA  + base] = ad_l[(j << 2) | k].y;
    }
    if (s == 3) out[OFF_MU + (b * TT + j) * 4 + k] = muk;  // j in [0,1024)
}

extern "C" void kernel_launch(void* const* d_in, const int* in_sizes, int n_in,
                              void* d_out, int out_size, void* d_ws, size_t ws_size,
                              hipStream_t stream) {
    const float* time_step = (const float*)d_in[0];
    const int*   event     = (const int*)  d_in[1];
    const int*   mkt       = (const int*)  d_in[2];
    const float* mw1 = (const float*)d_in[3];
    const float* mb1 = (const float*)d_in[4];
    const float* mw2 = (const float*)d_in[5];
    const float* mb2 = (const float*)d_in[6];
    const float* aw1 = (const float*)d_in[7];
    const float* ab1 = (const float*)d_in[8];
    const float* aw2 = (const float*)d_in[9];
    const float* ab2 = (const float*)d_in[10];
    const float* dw1 = (const float*)d_in[11];
    const float* db1 = (const float*)d_in[12];
    const float* dw2 = (const float*)d_in[13];
    const float* db2 = (const float*)d_in[14];
    float* ws  = (float*)d_ws;
    float* out = (float*)d_out;

    k_prep<<<1, 256, 0, stream>>>(time_step, mw1, mb1, mw2, mb2,
                                  aw1, ab1, aw2, ab2, dw1, db1, dw2, db2, ws);
    k_main<<<dim3(64, 8), 256, 0, stream>>>(event, mkt, ws, out);
}

// Round 2
// 100.546 us; speedup vs baseline: 1.0357x; 1.0357x over previous
//
#include <hip/hip_runtime.h>

#define TT 1024
#define BB 8
#define II 1023
// output offsets (floats)
#define OFF_INTENS 0
#define OFF_MU     32736          // 8*1023*4
#define OFF_ALPHA  65504          // + 8*1024*4
#define OFF_DELTA  98240          // + 8*1023*4

__device__ __forceinline__ float softplus_f(float x) {
    return fmaxf(x, 0.f) + log1pf(expf(-fabsf(x)));
}

// One fused kernel. Grid (64 jt, 8 b), 256 threads.
// Phase 1: stage ts row (float4), tids 64..163 compute the 48+48+4 MLP tables.
// Phase 2: tid 0 does a register-blocked SEQUENTIAL fp32 prefix scan (bitwise
//          np.cumsum order) of only the jt*16+16 entries this block needs,
//          while tids 64..255 expand the per-i (alpha,delta) LDS table.
// Phase 3: triangular excite sum. Thread map: bits[1:0]=s (i-split, i≡s mod 4),
//          bits[3:2]=k, bits[7:4]=jj (j = 16*jt+jj). ad_l float2 layout gives
//          conflict-free ds_read_b64 (lanes 0-15 cover all 32 banks once;
//          lanes 16+ are same-address broadcast).
__global__ __launch_bounds__(256) void k_fused(
    const float* __restrict__ time_step,
    const int* __restrict__ event, const int* __restrict__ mkt,
    const float* __restrict__ mw1, const float* __restrict__ mb1,
    const float* __restrict__ mw2, const float* __restrict__ mb2,
    const float* __restrict__ aw1, const float* __restrict__ ab1,
    const float* __restrict__ aw2, const float* __restrict__ ab2,
    const float* __restrict__ dw1, const float* __restrict__ db1,
    const float* __restrict__ dw2, const float* __restrict__ db2,
    float* __restrict__ out)
{
    __shared__ float  raw[TT];
    __shared__ float  pre[TT];
    __shared__ float2 tab[48];     // (e*3+s)*4+k -> (alpha, delta)
    __shared__ float  mu_s[4];
    __shared__ float2 ad_l[TT * 4];

    const int tid = threadIdx.x;
    const int jt  = blockIdx.x;
    const int b   = blockIdx.y;

    // ---- Phase 1: stage ts row + tiny MLP tables ----
    ((float4*)raw)[tid] = ((const float4*)(time_step + b * TT))[tid];

    if (tid >= 64 && tid < 160) {
        const int idx = tid - 64;
        const int c   = (idx < 48) ? idx : idx - 48;   // (e*3+s)*4+k
        const bool isA = idx < 48;
        const float* w1 = isA ? aw1 : dw1;
        const float* b1 = isA ? ab1 : db1;
        const float* w2 = isA ? aw2 : dw2;
        const float* b2 = isA ? ab2 : db2;
        const int e = c / 12, s = (c % 12) >> 2, k = c & 3;
        float acc = 0.f;
        #pragma unroll
        for (int n = 0; n < 16; ++n) {
            // reference add order: ((ev + st) + eye) + b1
            float h = w1[e * 16 + n] + w1[(4 + s) * 16 + n] + w1[(7 + k) * 16 + n] + b1[n];
            acc += fmaxf(h, 0.f) * w2[n];
        }
        const float v = softplus_f(acc + b2[0]);
        if (isA) tab[c].x = v; else tab[c].y = v;
    } else if (tid >= 160 && tid < 164) {
        const int k = tid - 160;
        float acc = 0.f;
        #pragma unroll
        for (int n = 0; n < 16; ++n)
            acc += fmaxf(mw1[k * 16 + n] + mb1[n], 0.f) * mw2[n];
        mu_s[k] = softplus_f(acc + mb2[0]);
    }
    __syncthreads();

    // ---- Phase 2: scan (tid 0) || ad table expansion (tids 64..255) ----
    if (tid == 0) {
        const int need = min(jt * 16 + 17, TT);   // p[0 .. need-1]
        const float4* r4 = (const float4*)raw;
        float4*       p4 = (float4*)pre;
        float run = 0.f;
        for (int t0 = 0; t0 < need; t0 += 16) {
            const int q = t0 >> 2;
            const float4 va = r4[q], vb = r4[q + 1], vc = r4[q + 2], vd = r4[q + 3];
            const float v[16] = {va.x, va.y, va.z, va.w, vb.x, vb.y, vb.z, vb.w,
                                 vc.x, vc.y, vc.z, vc.w, vd.x, vd.y, vd.z, vd.w};
            float o[16];
            #pragma unroll
            for (int u = 0; u < 16; ++u) {
                run += (t0 + u == 0) ? 0.f : v[u];   // skip raw[0]; p[0]=0
                o[u] = run;
            }
            p4[q]     = make_float4(o[0],  o[1],  o[2],  o[3]);
            p4[q + 1] = make_float4(o[4],  o[5],  o[6],  o[7]);
            p4[q + 2] = make_float4(o[8],  o[9],  o[10], o[11]);
            p4[q + 3] = make_float4(o[12], o[13], o[14], o[15]);
        }
    } else if (tid >= 64) {
        const int t = tid - 64;
        for (int i = t; i < TT; i += 192) {
            const int c = (event[b * TT + i] * 3 + mkt[b * TT + i]) << 2;
            const float2 v0 = tab[c], v1 = tab[c + 1], v2 = tab[c + 2], v3 = tab[c + 3];
            float4* dst = (float4*)&ad_l[i << 2];
            dst[0] = make_float4(v0.x, v0.y, v1.x, v1.y);
            dst[1] = make_float4(v2.x, v2.y, v3.x, v3.y);
        }
    }
    __syncthreads();

    // ---- Phase 3: triangular excite sum ----
    const int s  = tid & 3;
    const int k  = (tid >> 2) & 3;
    const int jj = tid >> 4;
    const int j  = jt * 16 + jj;

    float acc = 0.f;
    if (j < II) {
        const float tsj1 = pre[j + 1];
        #pragma unroll 4
        for (int i = s; i <= j; i += 4) {
            const float2 ad = ad_l[(i << 2) | k];
            float dt = tsj1 - pre[i];
            dt = (dt > 0.f) ? dt : 1e9f;
            acc += ad.x * __expf(-ad.y * dt);
        }
    }
    acc += __shfl_xor(acc, 1, 64);
    acc += __shfl_xor(acc, 2, 64);

    const float muk = mu_s[k];
    if (j < II) {
        const int base = (b * II + j) * 4 + k;
        if (s == 0)      out[OFF_INTENS + base] = muk + acc;
        else if (s == 1) out[OFF_ALPHA  + base] = ad_l[(j << 2) | k].x;
        else if (s == 2) out[OFF_DELTA  + base] = ad_l[(j << 2) | k].y;
    }
    if (s == 3) out[OFF_MU + (b * TT + j) * 4 + k] = muk;   // j in [0,1024)
}

extern "C" void kernel_launch(void* const* d_in, const int* in_sizes, int n_in,
                              void* d_out, int out_size, void* d_ws, size_t ws_size,
                              hipStream_t stream) {
    const float* time_step = (const float*)d_in[0];
    const int*   event     = (const int*)  d_in[1];
    const int*   mkt       = (const int*)  d_in[2];
    const float* mw1 = (const float*)d_in[3];
    const float* mb1 = (const float*)d_in[4];
    const float* mw2 = (const float*)d_in[5];
    const float* mb2 = (const float*)d_in[6];
    const float* aw1 = (const float*)d_in[7];
    const float* ab1 = (const float*)d_in[8];
    const float* aw2 = (const float*)d_in[9];
    const float* ab2 = (const float*)d_in[10];
    const float* dw1 = (const float*)d_in[11];
    const float* db1 = (const float*)d_in[12];
    const float* dw2 = (const float*)d_in[13];
    const float* db2 = (const float*)d_in[14];
    float* out = (float*)d_out;

    k_fused<<<dim3(64, 8), 256, 0, stream>>>(time_step, event, mkt,
                                             mw1, mb1, mw2, mb2,
                                             aw1, ab1, aw2, ab2,
                                             dw1, db1, dw2, db2, out);
}